// Round 5
// baseline (232.080 us; speedup 1.0000x reference)
//
#include <hip/hip_runtime.h>

#define EPSV 1e-5f
constexpr int Bb = 4, Cc = 64, Nn = 40960, Kk = 16, Dd = 128;
constexpr int G = 8;                       // point-tiles per block in pass B
constexpr int TPB = Nn / 16;               // tiles per batch = 2560

typedef float f32x4 __attribute__((ext_vector_type(4)));
typedef __bf16 bf16x8 __attribute__((ext_vector_type(8)));
typedef unsigned short us8 __attribute__((ext_vector_type(8)));
typedef unsigned short us4 __attribute__((ext_vector_type(4)));

__device__ inline unsigned short f2bf(float x) {
    unsigned u = __builtin_bit_cast(unsigned, x);
    u += 0x7FFFu + ((u >> 16) & 1u);   // RNE
    return (unsigned short)(u >> 16);
}

// ---------------------------------------------------------------------------
// Prep: fold BN scale into bf16 weights, precompute shifts.
__global__ __launch_bounds__(256) void prep_weights(
    const float* __restrict__ w1, const float* __restrict__ g1, const float* __restrict__ b1,
    const float* __restrict__ m1, const float* __restrict__ v1,
    const float* __restrict__ w2, const float* __restrict__ g2, const float* __restrict__ b2,
    const float* __restrict__ m2, const float* __restrict__ v2,
    const float* __restrict__ w3, const float* __restrict__ g3, const float* __restrict__ b3,
    const float* __restrict__ m3, const float* __restrict__ v3,
    unsigned short* __restrict__ w1s, unsigned short* __restrict__ w2s, unsigned short* __restrict__ w3s,
    float* __restrict__ sh1, float* __restrict__ sh2, float* __restrict__ sh3) {
    const int e = blockIdx.x * 256 + threadIdx.x;
    if (e < 4096) {
        const int o = e >> 6;
        const float sc = g1[o] * rsqrtf(v1[o] + EPSV);
        w1s[e] = f2bf(w1[e] * sc);
    } else if (e < 12288) {
        const int i = e - 4096, o = i >> 6;
        const float sc = g2[o] * rsqrtf(v2[o] + EPSV);
        w2s[i] = f2bf(w2[i] * sc);
    } else if (e < 20480) {
        const int i = e - 12288, o = i >> 6;
        const float sc = g3[o] * rsqrtf(v3[o] + EPSV);
        w3s[i] = f2bf(w3[i] * sc);
    }
    if (e < 64) sh1[e] = b1[e] - m1[e] * (g1[e] * rsqrtf(v1[e] + EPSV));
    else if (e < 192) { const int d = e - 64;  sh2[d] = b2[d] - m2[d] * (g2[d] * rsqrtf(v2[d] + EPSV)); }
    else if (e < 320) { const int d = e - 192; sh3[d] = b3[d] - m3[d] * (g3[d] * rsqrtf(v3[d] + EPSV)); }
}

// ---------------------------------------------------------------------------
// Pass A: G1 = sc1 * (W1 . f) as (B,N,64) bf16; optionally also ft = bf16
// transpose of f (B,N,64) for pass B's skip path. 64 points per block.
__global__ __launch_bounds__(256) void passA(const float* __restrict__ f,
                                             const unsigned short* __restrict__ w1s,
                                             unsigned short* __restrict__ G1,
                                             unsigned short* __restrict__ ft,
                                             int use_ft) {
    __shared__ float s[64 * 65];                            // [ch][pt]
    __shared__ __attribute__((aligned(16))) unsigned short sg1[64 * 72];  // [pt][ch]

    const int tid = threadIdx.x, w = tid >> 6, lane = tid & 63;
    const int c15 = lane & 15, q = lane >> 4;
    const int b = blockIdx.x / 640;
    const int n0 = (blockIdx.x % 640) * 64;

    // load fp32 tile: [64 ch][64 pts]
    const float* src = f + ((size_t)b * Cc + w * 16) * Nn + n0 + lane;
#pragma unroll
    for (int i = 0; i < 16; ++i) s[(w * 16 + i) * 65 + lane] = src[(size_t)i * Nn];

    // weight B-frags: out-channel o1 = w*16 + c15
    const int o1 = w * 16 + c15;
    bf16x8 bw1[2];
#pragma unroll
    for (int ks = 0; ks < 2; ++ks)
        bw1[ks] = __builtin_bit_cast(bf16x8, *(const uint4*)(w1s + o1 * 64 + ks * 32 + q * 8));
    __syncthreads();

    // ft store: thread (p = tid>>2, ck = tid&3) writes 32 B of bf16 row p
    if (use_ft) {
        const int p = tid >> 2, ck = tid & 3;
        us8 o0, o1v;
#pragma unroll
        for (int j = 0; j < 8; ++j) o0[j] = f2bf(s[(ck * 16 + j) * 65 + p]);
#pragma unroll
        for (int j = 0; j < 8; ++j) o1v[j] = f2bf(s[(ck * 16 + 8 + j) * 65 + p]);
        unsigned short* dst = ft + ((size_t)b * Nn + n0 + p) * 64 + ck * 16;
        *(us8*)dst = o0;
        *(us8*)(dst + 8) = o1v;
    }

#pragma unroll
    for (int mt = 0; mt < 4; ++mt) {
        const int pt = mt * 16 + c15;
        us8 A0, A1;
#pragma unroll
        for (int j = 0; j < 8; ++j) A0[j] = f2bf(s[(q * 8 + j) * 65 + pt]);
#pragma unroll
        for (int j = 0; j < 8; ++j) A1[j] = f2bf(s[(32 + q * 8 + j) * 65 + pt]);
        f32x4 g = {0.f, 0.f, 0.f, 0.f};
        g = __builtin_amdgcn_mfma_f32_16x16x32_bf16(__builtin_bit_cast(bf16x8, A0), bw1[0], g, 0, 0, 0);
        g = __builtin_amdgcn_mfma_f32_16x16x32_bf16(__builtin_bit_cast(bf16x8, A1), bw1[1], g, 0, 0, 0);
#pragma unroll
        for (int r = 0; r < 4; ++r) sg1[(mt * 16 + q * 4 + r) * 72 + o1] = f2bf(g[r]);
    }
    __syncthreads();

    // coalesced G1 store: thread (p = tid>>2, ck = tid&3) writes 32 B of row p
    {
        const int p = tid >> 2, ck = tid & 3;
        const uint4 v0 = *(const uint4*)(sg1 + p * 72 + ck * 16);
        const uint4 v1 = *(const uint4*)(sg1 + p * 72 + ck * 16 + 8);
        unsigned short* dst = G1 + ((size_t)b * Nn + n0 + p) * 64 + ck * 16;
        *(uint4*)dst = v0;
        *(uint4*)(dst + 8) = v1;
    }
}

// ---------------------------------------------------------------------------
// Pass B: gather G1 rows from global (L2/L3-resident), relu+sum -> h1 (LDS);
// then W2.h1 + W3.f_own via MFMA, direct coalesced f32x4 store (C-layout rows
// are 4 consecutive points of one d-channel -> 64 B/row/instr, same DRAM
// pattern as an LDS-staged store but without the round-trip + barrier).
__global__ __launch_bounds__(256, 4) void passB(
    const unsigned short* __restrict__ G1, const unsigned short* __restrict__ ft,
    const float* __restrict__ f, const int* __restrict__ idx,
    const unsigned short* __restrict__ w2s, const unsigned short* __restrict__ w3s,
    const float* __restrict__ sh1, const float* __restrict__ sh2, const float* __restrict__ sh3,
    float* __restrict__ out, int use_ft) {
    __shared__ __attribute__((aligned(16))) unsigned short s_h1[16 * 72];

    const int tid  = threadIdx.x;
    const int wave = tid >> 6;
    const int lane = tid & 63;
    const int c15  = lane & 15;
    const int q    = lane >> 4;
    const int pg   = tid >> 4;              // gather-phase point 0..15
    const int cg   = tid & 15;              // gather-phase channel group (4 ch)

    const int t0  = blockIdx.x * G;
    const int b   = t0 / TPB;               // 320 blocks per batch, G|TPB
    const int nb0 = (t0 - b * TPB) * 16;

    // weight B-frags (register-resident, bf16 pre-scaled)
    float sh2v[2], sh3v[2];
    bf16x8 bw2[2][2], bw3[2][2];
#pragma unroll
    for (int nt = 0; nt < 2; ++nt) {
        const int d = wave * 32 + nt * 16 + c15;
        sh2v[nt] = sh2[d];
        sh3v[nt] = sh3[d];
#pragma unroll
        for (int ks = 0; ks < 2; ++ks) {
            bw2[nt][ks] = __builtin_bit_cast(bf16x8, *(const uint4*)(w2s + d * 64 + ks * 32 + q * 8));
            bw3[nt][ks] = __builtin_bit_cast(bf16x8, *(const uint4*)(w3s + d * 64 + ks * 32 + q * 8));
        }
    }
    float shA[4];
#pragma unroll
    for (int j = 0; j < 4; ++j) shA[j] = sh1[cg * 4 + j];

    const unsigned short* G1b = G1 + (size_t)b * Nn * 64;
    const unsigned short* ftb = ft + (size_t)b * Nn * 64;
    const float* fb0 = f + (size_t)b * Cc * Nn;

    for (int g = 0; g < G; ++g) {
        const int n0 = nb0 + g * 16;

        // own-feature A-frags for the W3 skip path
        us8 F0, F1;
        if (use_ft) {
            const unsigned short* frow = ftb + (size_t)(n0 + c15) * 64;
            F0 = *(const us8*)(frow + q * 8);
            F1 = *(const us8*)(frow + 32 + q * 8);
        } else {
            const float* fown = fb0 + n0 + c15;
#pragma unroll
            for (int j = 0; j < 8; ++j) F0[j] = f2bf(fown[(size_t)(q * 8 + j) * Nn]);
#pragma unroll
            for (int j = 0; j < 8; ++j) F1[j] = f2bf(fown[(size_t)(32 + q * 8 + j) * Nn]);
        }

        // idx row `tid` of this tile (point tid>>4, neighbor tid&15)
        const int myidx = idx[((size_t)b * Nn + n0) * Kk + tid];

        // gather + relu-sum: thread (pg, cg) accumulates 4 channels over 16 nbrs
        float a0 = 0.f, a1 = 0.f, a2 = 0.f, a3 = 0.f;
#pragma unroll
        for (int k = 0; k < 16; ++k) {
            const int nb = __shfl(myidx, (pg & 3) * 16 + k, 64);
            const uint2 d2 = *(const uint2*)(G1b + (size_t)nb * 64 + cg * 4);
            const float f0 = __builtin_bit_cast(float, d2.x << 16);
            const float f1 = __builtin_bit_cast(float, d2.x & 0xffff0000u);
            const float f2v = __builtin_bit_cast(float, d2.y << 16);
            const float f3 = __builtin_bit_cast(float, d2.y & 0xffff0000u);
            a0 += fmaxf(f0 + shA[0], 0.f);
            a1 += fmaxf(f1 + shA[1], 0.f);
            a2 += fmaxf(f2v + shA[2], 0.f);
            a3 += fmaxf(f3 + shA[3], 0.f);
        }

        __syncthreads();                     // prev iter's s_h1 reads done
        us4 hv;
        hv[0] = f2bf(a0); hv[1] = f2bf(a1); hv[2] = f2bf(a2); hv[3] = f2bf(a3);
        *(us4*)(s_h1 + pg * 72 + cg * 4) = hv;
        __syncthreads();

        // GEMM2 (W2 . h1) + skip (W3 . f_own), direct store
        const unsigned short* h1row = s_h1 + c15 * 72;
        const bf16x8 ah0 = __builtin_bit_cast(bf16x8, *(const uint4*)(h1row + q * 8));
        const bf16x8 ah1 = __builtin_bit_cast(bf16x8, *(const uint4*)(h1row + 32 + q * 8));
        const bf16x8 af0 = __builtin_bit_cast(bf16x8, F0);
        const bf16x8 af1 = __builtin_bit_cast(bf16x8, F1);

#pragma unroll
        for (int nt = 0; nt < 2; ++nt) {
            f32x4 h2 = {sh2v[nt], sh2v[nt], sh2v[nt], sh2v[nt]};
            f32x4 s3 = {sh3v[nt], sh3v[nt], sh3v[nt], sh3v[nt]};
            h2 = __builtin_amdgcn_mfma_f32_16x16x32_bf16(ah0, bw2[nt][0], h2, 0, 0, 0);
            h2 = __builtin_amdgcn_mfma_f32_16x16x32_bf16(ah1, bw2[nt][1], h2, 0, 0, 0);
            s3 = __builtin_amdgcn_mfma_f32_16x16x32_bf16(af0, bw3[nt][0], s3, 0, 0, 0);
            s3 = __builtin_amdgcn_mfma_f32_16x16x32_bf16(af1, bw3[nt][1], s3, 0, 0, 0);
            const int d = wave * 32 + nt * 16 + c15;
            f32x4 o;
#pragma unroll
            for (int r = 0; r < 4; ++r) o[r] = fmaxf(h2[r], 0.f) + fmaxf(s3[r], 0.f);
            *(f32x4*)(out + ((size_t)b * Dd + d) * Nn + n0 + q * 4) = o;
        }
    }
}

extern "C" void kernel_launch(void* const* d_in, const int* in_sizes, int n_in,
                              void* d_out, int out_size, void* d_ws, size_t ws_size,
                              hipStream_t stream) {
    const float* feature = (const float*)d_in[0];
    const int*   neigh   = (const int*)d_in[1];
    const float* w1 = (const float*)d_in[2];
    const float* g1 = (const float*)d_in[3];
    const float* b1 = (const float*)d_in[4];
    const float* m1 = (const float*)d_in[5];
    const float* v1 = (const float*)d_in[6];
    const float* w2 = (const float*)d_in[7];
    const float* g2 = (const float*)d_in[8];
    const float* b2 = (const float*)d_in[9];
    const float* m2 = (const float*)d_in[10];
    const float* v2 = (const float*)d_in[11];
    const float* w3 = (const float*)d_in[12];
    const float* g3 = (const float*)d_in[13];
    const float* b3 = (const float*)d_in[14];
    const float* m3 = (const float*)d_in[15];
    const float* v3 = (const float*)d_in[16];
    float* out = (float*)d_out;

    constexpr size_t SZ = (size_t)Bb * Nn * 64 * 2;   // 20,971,520 B
    char* ws = (char*)d_ws;
    unsigned short* G1  = (unsigned short*)ws;
    unsigned short* ftp = (unsigned short*)(ws + SZ);
    const int use_ft = (ws_size >= 2 * SZ + 65536) ? 1 : 0;
    const size_t woff = use_ft ? 2 * SZ : SZ;
    unsigned short* w1s = (unsigned short*)(ws + woff);
    unsigned short* w2s = (unsigned short*)(ws + woff + 8192);
    unsigned short* w3s = (unsigned short*)(ws + woff + 24576);
    float* sh1 = (float*)(ws + woff + 40960);
    float* sh2 = (float*)(ws + woff + 41216);
    float* sh3 = (float*)(ws + woff + 41728);

    prep_weights<<<80, 256, 0, stream>>>(w1, g1, b1, m1, v1, w2, g2, b2, m2, v2,
                                         w3, g3, b3, m3, v3, w1s, w2s, w3s, sh1, sh2, sh3);
    passA<<<Bb * 640, 256, 0, stream>>>(feature, w1s, G1, ftp, use_ft);
    passB<<<(Bb * TPB) / G, 256, 0, stream>>>(G1, ftp, feature, neigh, w2s, w3s,
                                              sh1, sh2, sh3, out, use_ft);
}